// Round 5
// baseline (541.255 us; speedup 1.0000x reference)
//
#include <hip/hip_runtime.h>

#define N_ROWS 32768
#define DIMS 256
#define K_CODES 1024
#define MT 64      // rows per block
#define NCHUNK 256 // codes per chunk
#define KC 32      // K per LDS stage
#define SA 68      // As stride: 64 rows + 4 pad
#define SB 260     // Bs stride: 256 codes + 4 pad

static constexpr size_t SC_OFF  = 8388608;   // after quantized [32768*256] (float32 elements)
static constexpr size_t IDX_OFF = 8388612;   // after 4 scalars

__device__ inline float wsum64(float v){
  #pragma unroll
  for(int off=32; off; off>>=1) v += __shfl_xor(v, off, 64);
  return v;
}

// ---- row squared norm: bit-exact numpy AVX512 SIMD pairwise emulation ------
// np.sum(a*a, -1), n=256: pairwise split 128+128; per 128-block 8 vector
// accumulators lanewise-combined, then (+8)(+4)(+2)(+1) butterfly. Squares
// rounded before summing; __fmul_rn/__fadd_rn forbid FMA contraction.
__device__ __attribute__((noinline)) float rowsq_np512(const float* __restrict__ s0){
  float blk[2];
  #pragma unroll
  for(int bb=0; bb<2; bb++){
    const float* s = s0 + bb*128;
    float q[128];
    #pragma unroll
    for(int i=0;i<32;i++){
      float4 v = *(const float4*)(s + i*4);
      q[i*4+0]=__fmul_rn(v.x,v.x); q[i*4+1]=__fmul_rn(v.y,v.y);
      q[i*4+2]=__fmul_rn(v.z,v.z); q[i*4+3]=__fmul_rn(v.w,v.w);
    }
    float v16[16];
    #pragma unroll
    for(int l=0;l<16;l++)
      v16[l] = __fadd_rn(__fadd_rn(__fadd_rn(q[l],     q[l+16]),
                                   __fadd_rn(q[l+32],  q[l+48])),
                         __fadd_rn(__fadd_rn(q[l+64],  q[l+80]),
                                   __fadd_rn(q[l+96],  q[l+112])));
    float w8[8];
    #pragma unroll
    for(int l=0;l<8;l++) w8[l] = __fadd_rn(v16[l], v16[l+8]);
    float u4[4];
    #pragma unroll
    for(int l=0;l<4;l++) u4[l] = __fadd_rn(w8[l], w8[l+4]);
    float t0 = __fadd_rn(u4[0], u4[2]);
    float t1 = __fadd_rn(u4[1], u4[3]);
    blk[bb] = __fadd_rn(t0, t1);
  }
  return __fadd_rn(blk[0], blk[1]);
}

// --------- fused: norms + distances + argmin + softmax + quant gather -------
// R5: 8x8 register tile at R2's proven register profile.
//  * 256 thr = 32 tx (codes) x 8 ty (8 rows each): acc[8][8]=64 regs, the
//    exact a4p[2]+b4p[8]=40-reg staging that compiled to VGPR=128 in R2.
//    R3/R4's acc[8][16]=128-reg tile forced scratch spills (WRITE_SIZE
//    87->265 MB); this backs off to the spill-free point.
//  * per k: 2 A b128 (2-address broadcast) + 2 B b128 (32-lane contiguous)
//    = 4 LDS instr / 64 FMA (R2: 5) -> LDS pipe ~164us vs 109us VALU floor.
//  * MT=64, 4 chunks, grid 512 -> 2 blocks/CU (93 KB LDS), 2 waves/SIMD;
//    amdgpu_waves_per_eu(2,2) pins the allocator at that occupancy so it
//    allocates ~160 VGPR instead of spilling toward an unreachable 4 w/EU.
// The per-(row,code) single-accumulator ascending-k fmaf chain is unchanged
// -> distances remain bit-exact vs the CPU BLAS reference.
__global__ __launch_bounds__(256)
__attribute__((amdgpu_waves_per_eu(2,2)))
void fused_argmin_kernel(
    const float* __restrict__ X, const float* __restrict__ CB,
    float* __restrict__ hist, float* __restrict__ acc_sc,
    float* __restrict__ out)
{
  __shared__ __align__(16) float As[KC][SA];
  __shared__ __align__(16) float Bs[KC][SB];
  __shared__ __align__(16) float cs_lds[K_CODES];
  __shared__ __align__(16) float xs_lds[MT];
  __shared__ int sk[MT];
  const int t  = threadIdx.x;
  const int tx = t & 31, ty = t >> 5;   // 32 tx (codes) x 8 ty (8 rows each)
  const int m0 = blockIdx.x * MT;

  // ---- prologue: row norms (bit-exact numpy emulation) into LDS -----------
  #pragma unroll
  for(int c=0;c<4;c++)
    cs_lds[c*256 + t] = rowsq_np512(CB + (size_t)(c*256 + t)*DIMS);
  if(t < MT)
    xs_lds[t] = rowsq_np512(X + (size_t)(m0 + t)*DIMS);

  const int arow = t >> 2;            // 0..63 : row within tile
  const int acol = (t & 3) * 8;       // 0,8,16,24 : k offset (8 floats/thread)
  const float* Ag = X + (size_t)(m0 + arow)*DIMS + acol;

  // stage-0 register prefetch (nc=0, kc=0); overlaps the prologue barrier
  float4 a4p[2], b4p[8];
  #pragma unroll
  for(int q=0;q<2;q++) a4p[q] = *(const float4*)(Ag + q*4);
  {
    const float* Bg = CB + (size_t)t*DIMS;   // code t of chunk 0
    #pragma unroll
    for(int q=0;q<8;q++) b4p[q] = *(const float4*)(Bg + q*4);
  }
  __syncthreads();                    // cs_lds/xs_lds ready

  float xs_[8];
  { float4 x0 = *(const float4*)&xs_lds[ty*8];
    float4 x1 = *(const float4*)&xs_lds[ty*8+4];
    xs_[0]=x0.x; xs_[1]=x0.y; xs_[2]=x0.z; xs_[3]=x0.w;
    xs_[4]=x1.x; xs_[5]=x1.y; xs_[6]=x1.z; xs_[7]=x1.w; }

  // per-thread online state for rows ty*8 + {0..7}
  float dm[8]; int km[8]; float Ss[8], Ts[8];

  for(int nc=0; nc<4; nc++){
    const int n0c = nc*NCHUNK;
    float acc[8][8];
    #pragma unroll
    for(int i=0;i<8;i++)
      #pragma unroll
      for(int j=0;j<8;j++) acc[i][j]=0.f;

    // K-chain: strictly ascending k=0..255, one fmaf chain per (row,code)
    for(int kc=0;kc<8;kc++){
      __syncthreads();
      // commit prefetched stage to LDS (k-major scatter)
      #pragma unroll
      for(int q=0;q<2;q++){
        As[acol+q*4+0][arow]=a4p[q].x; As[acol+q*4+1][arow]=a4p[q].y;
        As[acol+q*4+2][arow]=a4p[q].z; As[acol+q*4+3][arow]=a4p[q].w;
      }
      #pragma unroll
      for(int q=0;q<8;q++){
        Bs[q*4+0][t]=b4p[q].x; Bs[q*4+1][t]=b4p[q].y;
        Bs[q*4+2][t]=b4p[q].z; Bs[q*4+3][t]=b4p[q].w;
      }
      __syncthreads();
      // prefetch next stage; latency hides under the 2048-FMA compute phase
      {
        int nkc = kc+1, nnc = nc;
        if(nkc==8){ nkc=0; nnc=(nc+1)&3; }
        const float* An = Ag + nkc*KC;
        const float* Bn = CB + (size_t)(nnc*NCHUNK + t)*DIMS + nkc*KC;
        #pragma unroll
        for(int q=0;q<2;q++) a4p[q]=*(const float4*)(An + q*4);
        #pragma unroll
        for(int q=0;q<8;q++) b4p[q]=*(const float4*)(Bn + q*4);
      }
      #pragma unroll
      for(int k=0;k<KC;k++){
        float4 a0 = *(const float4*)&As[k][ty*8];
        float4 a1 = *(const float4*)&As[k][ty*8+4];
        float4 b0 = *(const float4*)&Bs[k][tx*4];
        float4 b1 = *(const float4*)&Bs[k][128 + tx*4];
        float a_[8]={a0.x,a0.y,a0.z,a0.w, a1.x,a1.y,a1.z,a1.w};
        float b_[8]={b0.x,b0.y,b0.z,b0.w, b1.x,b1.y,b1.z,b1.w};
        #pragma unroll
        for(int r=0;r<8;r++)
          #pragma unroll
          for(int j=0;j<8;j++)
            acc[r][j] = fmaf(a_[r], b_[j], acc[r][j]);
      }
    }

    // ---- chunk epilogue: d = sqrt(max(fl(fl(xs+cs) - 2*dot), 0)) -----------
    float csv[8];
    { float4 c0 = *(const float4*)&cs_lds[n0c + tx*4];
      float4 c1 = *(const float4*)&cs_lds[n0c + 128 + tx*4];
      csv[0]=c0.x; csv[1]=c0.y; csv[2]=c0.z; csv[3]=c0.w;
      csv[4]=c1.x; csv[5]=c1.y; csv[6]=c1.z; csv[7]=c1.w; }
    #pragma unroll
    for(int i=0;i<8;i++){
      float xs = xs_[i];
      float d[8];
      #pragma unroll
      for(int j=0;j<8;j++){
        // contraction-safe: 2*acc exact, fl(t - 2*acc)
        float d2 = (xs + csv[j]) - 2.0f*acc[i][j];
        d[j] = sqrtf(fmaxf(d2, 0.f));
      }
      // thread-local argmin, ascending kidx, strict < (first-occurrence tie)
      float dl = INFINITY; int kl = 0;
      #pragma unroll
      for(int j=0;j<8;j++){
        int kidx = n0c + (j>>2)*128 + tx*4 + (j&3);   // ascending in j
        if(d[j] < dl){ dl = d[j]; kl = kidx; }
      }
      // butterfly across the 32 tx lanes of this row group
      #pragma unroll
      for(int off=1; off<32; off<<=1){
        float od = __shfl_xor(dl, off, 64);
        int   ok = __shfl_xor(kl, off, 64);
        if(od < dl || (od == dl && ok < kl)){ dl = od; kl = ok; }
      }
      // chunk softmax stats shifted at chunk min: l = (dl - d)*100 <= 0
      float s1=0.f, t2s=0.f;
      #pragma unroll
      for(int j=0;j<8;j++){
        float l = (dl - d[j])*100.0f;
        float e = expf(l);
        s1 += e; t2s = fmaf(e, l, t2s);
      }
      #pragma unroll
      for(int off=1; off<32; off<<=1){
        s1  += __shfl_xor(s1,  off, 64);
        t2s += __shfl_xor(t2s, off, 64);
      }
      if(nc == 0){
        dm[i]=dl; km[i]=kl; Ss[i]=s1; Ts[i]=t2s;
      } else {
        if(dl < dm[i]){                      // strict <: tie keeps old (smaller idx)
          float del = 100.0f*(dl - dm[i]); float al = expf(del);
          Ts[i] = al*(Ts[i] + Ss[i]*del) + t2s;
          Ss[i] = al*Ss[i] + s1;
          dm[i] = dl; km[i] = kl;
        } else {
          float del = 100.0f*(dm[i] - dl); float al = expf(del);
          Ts[i] += al*(t2s + s1*del);
          Ss[i] += al*s1;
        }
      }
    }
  }

  // ---- final per-row writes (one owner thread per row group: tx==0)
  float plogp = 0.f;
  if(tx == 0){
    #pragma unroll
    for(int i=0;i<8;i++){
      int n = m0 + ty*8 + i;
      out[IDX_OFF + n] = (float)km[i];
      sk[ty*8 + i] = km[i];
      atomicAdd(hist + km[i], 1.0f);
      plogp += Ts[i]/Ss[i] - logf(Ss[i]);
    }
  }
  plogp = wsum64(plogp);
  if((t & 63) == 0) atomicAdd(acc_sc + 1, plogp);

  // ---- fused quant gather + mse -------------------------------------------
  __syncthreads();                 // sk[] visible to all waves
  {
    int w = t>>6, lane = t&63;     // 4 waves x 16 rows
    int row0 = w*16;
    float mse = 0.f;
    for(int r=0;r<16;r++){
      int n = m0 + row0 + r;
      int k = sk[row0 + r];
      float4 cb4 = *(const float4*)(CB + (size_t)k*DIMS + lane*4);
      float4 x4  = *(const float4*)(X  + (size_t)n*DIMS + lane*4);
      float e0=x4.x-cb4.x, e1=x4.y-cb4.y, e2=x4.z-cb4.z, e3=x4.w-cb4.w;
      mse += e0*e0 + e1*e1 + e2*e2 + e3*e3;
      *reinterpret_cast<float4*>(out + (size_t)n*DIMS + lane*4) = cb4;
    }
    mse = wsum64(mse);
    if(lane==0) atomicAdd(acc_sc+0, mse);
  }
}

// ---------------- finalize scalars (float32) --------------------------------
__global__ __launch_bounds__(256) void finalize_kernel(const float* __restrict__ hist,
                                                       const float* __restrict__ acc_sc,
                                                       float* __restrict__ out){
  __shared__ float red[256];
  int t = threadIdx.x;
  float s = 0.f;
  #pragma unroll
  for(int c=0;c<4;c++){
    float ap = hist[c*256 + t] * (1.0f/32768.0f);   // avg_probs ~ argmin histogram
    s += ap * logf(ap + 1e-5f);
  }
  red[t] = s; __syncthreads();
  for(int off=128; off; off>>=1){
    if(t<off) red[t]+=red[t+off];
    __syncthreads();
  }
  if(t==0){
    float avg_entropy    = -red[0];
    float mse            = acc_sc[0] * (1.0f/8388608.0f);
    float sample_entropy = -(acc_sc[1] * (1.0f/32768.0f));
    float commit = 0.5f*mse*0.25f;
    float cbl    = 0.5f*mse;
    float ent    = (sample_entropy - avg_entropy)*0.1f;
    float vq     = cbl + commit + ent;
    out[SC_OFF+0] = vq;
    out[SC_OFF+1] = commit;
    out[SC_OFF+2] = cbl;
    out[SC_OFF+3] = ent;
  }
}

extern "C" void kernel_launch(void* const* d_in, const int* in_sizes, int n_in,
                              void* d_out, int out_size, void* d_ws, size_t ws_size,
                              hipStream_t stream){
  const float* X  = (const float*)d_in[0];
  const float* CB = (const float*)d_in[1];
  float* out = (float*)d_out;                        // float32 output buffer
  float* hist    = (float*)d_ws;                     // [1024]
  float* acc_sc  = hist + K_CODES;                   // [2]: mse, plogp

  hipMemsetAsync(hist, 0, (K_CODES+2)*sizeof(float), stream);
  fused_argmin_kernel<<<N_ROWS/MT, 256, 0, stream>>>(X, CB, hist, acc_sc, out);
  finalize_kernel    <<<1, 256, 0, stream>>>(hist, acc_sc, out);
}

// Round 6
// 427.772 us; speedup vs baseline: 1.2653x; 1.2653x over previous
//
#include <hip/hip_runtime.h>

#define N_ROWS 32768
#define DIMS 256
#define K_CODES 1024
#define MT 64      // rows per block
#define NCHUNK 256 // codes per chunk
#define KC 32      // K per LDS stage
#define SA 68      // As stride: 64 rows + 4 pad
#define SB 260     // Bs stride: 256 codes + 4 pad

static constexpr size_t SC_OFF  = 8388608;   // after quantized [32768*256] (float32 elements)
static constexpr size_t IDX_OFF = 8388612;   // after 4 scalars

__device__ inline float wsum64(float v){
  #pragma unroll
  for(int off=32; off; off>>=1) v += __shfl_xor(v, off, 64);
  return v;
}

// ---- row squared norms: bit-exact numpy AVX512 emulation, lane-cooperative -
// np.sum(a*a, -1), n=256: pairwise split 128+128. Per 128-block: 8 AVX512
// accumulators r_j combined lanewise ((r0+r1)+(r2+r3))+((r4+r5)+(r6+r7)),
// then _mm512_reduce_add_ps butterfly (+8)(+4)(+2)(+1). Mapping: lane l of a
// 16-lane group holds vector-lane l; q[j] = fl(a[16j+l]^2); the shfl_xor
// butterfly reproduces the reduce order exactly (self-first operand order;
// commuted pairs round identically). 16 lanes/row -> 64 B coalesced loads,
// ~8 VGPRs (R5's in-kernel q[128] version spilled ~0.5 GB of scratch).
__global__ __launch_bounds__(256) void rowsq_np512_kernel(const float* __restrict__ X,
                                                          const float* __restrict__ CB,
                                                          float* __restrict__ xsq,
                                                          float* __restrict__ csq){
  const int t = threadIdx.x;
  const int wv = t >> 6, l = t & 63;
  const int sub = l >> 4, li = l & 15;      // 4 rows per wave, 16 lanes per row
  #pragma unroll
  for(int p=0; p<4; p++){
    int r = blockIdx.x*64 + p*16 + wv*4 + sub;   // 528 blocks * 64 = 33792 rows
    const float* s0; float* dst;
    if(r < K_CODES){ s0 = CB + (size_t)r*DIMS; dst = csq + r; }
    else { s0 = X + (size_t)(r - K_CODES)*DIMS; dst = xsq + (r - K_CODES); }
    float blk[2];
    #pragma unroll
    for(int bb=0; bb<2; bb++){
      float q[8];
      #pragma unroll
      for(int j=0;j<8;j++){
        float a = s0[bb*128 + j*16 + li];
        q[j] = __fmul_rn(a, a);
      }
      float v = __fadd_rn(__fadd_rn(__fadd_rn(q[0],q[1]), __fadd_rn(q[2],q[3])),
                          __fadd_rn(__fadd_rn(q[4],q[5]), __fadd_rn(q[6],q[7])));
      v = __fadd_rn(v, __shfl_xor(v, 8, 64));
      v = __fadd_rn(v, __shfl_xor(v, 4, 64));
      v = __fadd_rn(v, __shfl_xor(v, 2, 64));
      v = __fadd_rn(v, __shfl_xor(v, 1, 64));
      blk[bb] = v;
    }
    if(li == 0) *dst = __fadd_rn(blk[0], blk[1]);
  }
}

// --------- fused: distances + argmin + softmax + quant gather ---------------
// R6: R5's 8x8 hot loop (4 ds_read_b128 per 64 FMAs, conflict-free) with the
// spilling in-kernel norm prologue removed — norms come precomputed from the
// coalesced rowsq kernel; prologue is a pure float4 copy into LDS.
//  * 256 thr = 32 tx (codes) x 8 ty (8 rows each): acc[8][8]=64 regs + 40
//    staging regs = R2's proven VGPR=128 spill-free profile.
//  * B-read: 32 lanes x float4 contiguous (conflict-free, 2-way bcast);
//    A-read: 2-address broadcast. Per CU per k: LDS ~balanced vs VALU floor.
// The per-(row,code) single-accumulator ascending-k fmaf chain is unchanged
// -> distances remain bit-exact vs the CPU BLAS reference.
__global__ __launch_bounds__(256,2) void fused_argmin_kernel(
    const float* __restrict__ X, const float* __restrict__ CB,
    const float* __restrict__ xsq, const float* __restrict__ csq,
    float* __restrict__ hist, float* __restrict__ acc_sc,
    float* __restrict__ out)
{
  __shared__ __align__(16) float As[KC][SA];
  __shared__ __align__(16) float Bs[KC][SB];
  __shared__ __align__(16) float cs_lds[K_CODES];
  __shared__ __align__(16) float xs_lds[MT];
  __shared__ int sk[MT];
  const int t  = threadIdx.x;
  const int tx = t & 31, ty = t >> 5;   // 32 tx (codes) x 8 ty (8 rows each)
  const int m0 = blockIdx.x * MT;

  // ---- prologue: copy precomputed norms into LDS (coalesced) --------------
  reinterpret_cast<float4*>(cs_lds)[t] = reinterpret_cast<const float4*>(csq)[t];
  if(t < 16)
    reinterpret_cast<float4*>(xs_lds)[t] = reinterpret_cast<const float4*>(xsq + m0)[t];

  const int arow = t >> 2;            // 0..63 : row within tile
  const int acol = (t & 3) * 8;       // 0,8,16,24 : k offset (8 floats/thread)
  const float* Ag = X + (size_t)(m0 + arow)*DIMS + acol;

  // stage-0 register prefetch (nc=0, kc=0); overlaps the prologue barrier
  float4 a4p[2], b4p[8];
  #pragma unroll
  for(int q=0;q<2;q++) a4p[q] = *(const float4*)(Ag + q*4);
  {
    const float* Bg = CB + (size_t)t*DIMS;   // code t of chunk 0
    #pragma unroll
    for(int q=0;q<8;q++) b4p[q] = *(const float4*)(Bg + q*4);
  }
  __syncthreads();                    // cs_lds/xs_lds ready

  float xs_[8];
  { float4 x0 = *(const float4*)&xs_lds[ty*8];
    float4 x1 = *(const float4*)&xs_lds[ty*8+4];
    xs_[0]=x0.x; xs_[1]=x0.y; xs_[2]=x0.z; xs_[3]=x0.w;
    xs_[4]=x1.x; xs_[5]=x1.y; xs_[6]=x1.z; xs_[7]=x1.w; }

  // per-thread online state for rows ty*8 + {0..7}
  float dm[8]; int km[8]; float Ss[8], Ts[8];

  for(int nc=0; nc<4; nc++){
    const int n0c = nc*NCHUNK;
    float acc[8][8];
    #pragma unroll
    for(int i=0;i<8;i++)
      #pragma unroll
      for(int j=0;j<8;j++) acc[i][j]=0.f;

    // K-chain: strictly ascending k=0..255, one fmaf chain per (row,code)
    for(int kc=0;kc<8;kc++){
      __syncthreads();
      // commit prefetched stage to LDS (k-major scatter)
      #pragma unroll
      for(int q=0;q<2;q++){
        As[acol+q*4+0][arow]=a4p[q].x; As[acol+q*4+1][arow]=a4p[q].y;
        As[acol+q*4+2][arow]=a4p[q].z; As[acol+q*4+3][arow]=a4p[q].w;
      }
      #pragma unroll
      for(int q=0;q<8;q++){
        Bs[q*4+0][t]=b4p[q].x; Bs[q*4+1][t]=b4p[q].y;
        Bs[q*4+2][t]=b4p[q].z; Bs[q*4+3][t]=b4p[q].w;
      }
      __syncthreads();
      // prefetch next stage; latency hides under the 2048-FMA compute phase
      {
        int nkc = kc+1, nnc = nc;
        if(nkc==8){ nkc=0; nnc=(nc+1)&3; }
        const float* An = Ag + nkc*KC;
        const float* Bn = CB + (size_t)(nnc*NCHUNK + t)*DIMS + nkc*KC;
        #pragma unroll
        for(int q=0;q<2;q++) a4p[q]=*(const float4*)(An + q*4);
        #pragma unroll
        for(int q=0;q<8;q++) b4p[q]=*(const float4*)(Bn + q*4);
      }
      #pragma unroll
      for(int k=0;k<KC;k++){
        float4 a0 = *(const float4*)&As[k][ty*8];
        float4 a1 = *(const float4*)&As[k][ty*8+4];
        float4 b0 = *(const float4*)&Bs[k][tx*4];
        float4 b1 = *(const float4*)&Bs[k][128 + tx*4];
        float a_[8]={a0.x,a0.y,a0.z,a0.w, a1.x,a1.y,a1.z,a1.w};
        float b_[8]={b0.x,b0.y,b0.z,b0.w, b1.x,b1.y,b1.z,b1.w};
        #pragma unroll
        for(int r=0;r<8;r++)
          #pragma unroll
          for(int j=0;j<8;j++)
            acc[r][j] = fmaf(a_[r], b_[j], acc[r][j]);
      }
    }

    // ---- chunk epilogue: d = sqrt(max(fl(fl(xs+cs) - 2*dot), 0)) -----------
    float csv[8];
    { float4 c0 = *(const float4*)&cs_lds[n0c + tx*4];
      float4 c1 = *(const float4*)&cs_lds[n0c + 128 + tx*4];
      csv[0]=c0.x; csv[1]=c0.y; csv[2]=c0.z; csv[3]=c0.w;
      csv[4]=c1.x; csv[5]=c1.y; csv[6]=c1.z; csv[7]=c1.w; }
    #pragma unroll
    for(int i=0;i<8;i++){
      float xs = xs_[i];
      float d[8];
      #pragma unroll
      for(int j=0;j<8;j++){
        // contraction-safe: 2*acc exact, fl(t - 2*acc)
        float d2 = (xs + csv[j]) - 2.0f*acc[i][j];
        d[j] = sqrtf(fmaxf(d2, 0.f));
      }
      // thread-local argmin, ascending kidx, strict < (first-occurrence tie)
      float dl = INFINITY; int kl = 0;
      #pragma unroll
      for(int j=0;j<8;j++){
        int kidx = n0c + (j>>2)*128 + tx*4 + (j&3);   // ascending in j
        if(d[j] < dl){ dl = d[j]; kl = kidx; }
      }
      // butterfly across the 32 tx lanes of this row group
      #pragma unroll
      for(int off=1; off<32; off<<=1){
        float od = __shfl_xor(dl, off, 64);
        int   ok = __shfl_xor(kl, off, 64);
        if(od < dl || (od == dl && ok < kl)){ dl = od; kl = ok; }
      }
      // chunk softmax stats shifted at chunk min: l = (dl - d)*100 <= 0
      float s1=0.f, t2s=0.f;
      #pragma unroll
      for(int j=0;j<8;j++){
        float l = (dl - d[j])*100.0f;
        float e = expf(l);
        s1 += e; t2s = fmaf(e, l, t2s);
      }
      #pragma unroll
      for(int off=1; off<32; off<<=1){
        s1  += __shfl_xor(s1,  off, 64);
        t2s += __shfl_xor(t2s, off, 64);
      }
      if(nc == 0){
        dm[i]=dl; km[i]=kl; Ss[i]=s1; Ts[i]=t2s;
      } else {
        if(dl < dm[i]){                      // strict <: tie keeps old (smaller idx)
          float del = 100.0f*(dl - dm[i]); float al = expf(del);
          Ts[i] = al*(Ts[i] + Ss[i]*del) + t2s;
          Ss[i] = al*Ss[i] + s1;
          dm[i] = dl; km[i] = kl;
        } else {
          float del = 100.0f*(dm[i] - dl); float al = expf(del);
          Ts[i] += al*(t2s + s1*del);
          Ss[i] += al*s1;
        }
      }
    }
  }

  // ---- final per-row writes (one owner thread per row group: tx==0)
  float plogp = 0.f;
  if(tx == 0){
    #pragma unroll
    for(int i=0;i<8;i++){
      int n = m0 + ty*8 + i;
      out[IDX_OFF + n] = (float)km[i];
      sk[ty*8 + i] = km[i];
      atomicAdd(hist + km[i], 1.0f);
      plogp += Ts[i]/Ss[i] - logf(Ss[i]);
    }
  }
  plogp = wsum64(plogp);
  if((t & 63) == 0) atomicAdd(acc_sc + 1, plogp);

  // ---- fused quant gather + mse -------------------------------------------
  __syncthreads();                 // sk[] visible to all waves
  {
    int w = t>>6, lane = t&63;     // 4 waves x 16 rows
    int row0 = w*16;
    float mse = 0.f;
    for(int r=0;r<16;r++){
      int n = m0 + row0 + r;
      int k = sk[row0 + r];
      float4 cb4 = *(const float4*)(CB + (size_t)k*DIMS + lane*4);
      float4 x4  = *(const float4*)(X  + (size_t)n*DIMS + lane*4);
      float e0=x4.x-cb4.x, e1=x4.y-cb4.y, e2=x4.z-cb4.z, e3=x4.w-cb4.w;
      mse += e0*e0 + e1*e1 + e2*e2 + e3*e3;
      *reinterpret_cast<float4*>(out + (size_t)n*DIMS + lane*4) = cb4;
    }
    mse = wsum64(mse);
    if(lane==0) atomicAdd(acc_sc+0, mse);
  }
}

// ---------------- finalize scalars (float32) --------------------------------
__global__ __launch_bounds__(256) void finalize_kernel(const float* __restrict__ hist,
                                                       const float* __restrict__ acc_sc,
                                                       float* __restrict__ out){
  __shared__ float red[256];
  int t = threadIdx.x;
  float s = 0.f;
  #pragma unroll
  for(int c=0;c<4;c++){
    float ap = hist[c*256 + t] * (1.0f/32768.0f);   // avg_probs ~ argmin histogram
    s += ap * logf(ap + 1e-5f);
  }
  red[t] = s; __syncthreads();
  for(int off=128; off; off>>=1){
    if(t<off) red[t]+=red[t+off];
    __syncthreads();
  }
  if(t==0){
    float avg_entropy    = -red[0];
    float mse            = acc_sc[0] * (1.0f/8388608.0f);
    float sample_entropy = -(acc_sc[1] * (1.0f/32768.0f));
    float commit = 0.5f*mse*0.25f;
    float cbl    = 0.5f*mse;
    float ent    = (sample_entropy - avg_entropy)*0.1f;
    float vq     = cbl + commit + ent;
    out[SC_OFF+0] = vq;
    out[SC_OFF+1] = commit;
    out[SC_OFF+2] = cbl;
    out[SC_OFF+3] = ent;
  }
}

extern "C" void kernel_launch(void* const* d_in, const int* in_sizes, int n_in,
                              void* d_out, int out_size, void* d_ws, size_t ws_size,
                              hipStream_t stream){
  const float* X  = (const float*)d_in[0];
  const float* CB = (const float*)d_in[1];
  float* out = (float*)d_out;                        // float32 output buffer
  float* xsq     = (float*)d_ws;                     // [32768]
  float* csq     = xsq + N_ROWS;                     // [1024]
  float* hist    = csq + K_CODES;                    // [1024]
  float* acc_sc  = hist + K_CODES;                   // [2]: mse, plogp

  hipMemsetAsync(hist, 0, (K_CODES+2)*sizeof(float), stream);
  rowsq_np512_kernel <<<(K_CODES+N_ROWS)/64, 256, 0, stream>>>(X, CB, xsq, csq);
  fused_argmin_kernel<<<N_ROWS/MT, 256, 0, stream>>>(X, CB, xsq, csq, hist, acc_sc, out);
  finalize_kernel    <<<1, 256, 0, stream>>>(hist, acc_sc, out);
}

// Round 7
// 367.056 us; speedup vs baseline: 1.4746x; 1.1654x over previous
//
#include <hip/hip_runtime.h>

#define N_ROWS 32768
#define DIMS 256
#define K_CODES 1024
#define MT 64      // rows per block
#define NCHUNK 256 // codes per chunk
#define KC 16      // K per LDS stage (16: halves staging registers vs 32)
#define SA 68      // As stride: 64 rows + 4 pad
#define SB 260     // Bs stride: 256 codes + 4 pad

static constexpr size_t SC_OFF  = 8388608;   // after quantized [32768*256] (float32 elements)
static constexpr size_t IDX_OFF = 8388612;   // after 4 scalars

__device__ inline float wsum64(float v){
  #pragma unroll
  for(int off=32; off; off>>=1) v += __shfl_xor(v, off, 64);
  return v;
}

// ---- row squared norms: bit-exact numpy AVX512 emulation, lane-cooperative -
// np.sum(a*a, -1), n=256: pairwise split 128+128. Per 128-block: 8 AVX512
// accumulators r_j combined lanewise ((r0+r1)+(r2+r3))+((r4+r5)+(r6+r7)),
// then _mm512_reduce_add_ps butterfly (+8)(+4)(+2)(+1). Lane l of a 16-lane
// group holds vector-lane l; the shfl_xor butterfly reproduces the reduce
// order exactly. 16 lanes/row -> 64 B coalesced loads, ~8 VGPRs.
__global__ __launch_bounds__(256) void rowsq_np512_kernel(const float* __restrict__ X,
                                                          const float* __restrict__ CB,
                                                          float* __restrict__ xsq,
                                                          float* __restrict__ csq){
  const int t = threadIdx.x;
  const int wv = t >> 6, l = t & 63;
  const int sub = l >> 4, li = l & 15;      // 4 rows per wave, 16 lanes per row
  #pragma unroll
  for(int p=0; p<4; p++){
    int r = blockIdx.x*64 + p*16 + wv*4 + sub;   // 528 blocks * 64 = 33792 rows
    const float* s0; float* dst;
    if(r < K_CODES){ s0 = CB + (size_t)r*DIMS; dst = csq + r; }
    else { s0 = X + (size_t)(r - K_CODES)*DIMS; dst = xsq + (r - K_CODES); }
    float blk[2];
    #pragma unroll
    for(int bb=0; bb<2; bb++){
      float q[8];
      #pragma unroll
      for(int j=0;j<8;j++){
        float a = s0[bb*128 + j*16 + li];
        q[j] = __fmul_rn(a, a);
      }
      float v = __fadd_rn(__fadd_rn(__fadd_rn(q[0],q[1]), __fadd_rn(q[2],q[3])),
                          __fadd_rn(__fadd_rn(q[4],q[5]), __fadd_rn(q[6],q[7])));
      v = __fadd_rn(v, __shfl_xor(v, 8, 64));
      v = __fadd_rn(v, __shfl_xor(v, 4, 64));
      v = __fadd_rn(v, __shfl_xor(v, 2, 64));
      v = __fadd_rn(v, __shfl_xor(v, 1, 64));
      blk[bb] = v;
    }
    if(li == 0) *dst = __fadd_rn(blk[0], blk[1]);
  }
}

// --------- fused: distances + argmin + softmax + quant gather ---------------
// R7: register-pressure surgery on R6's 8x8 hot loop (which had the right
// LDS ratio but spilled ~270 MB of scratch at the allocator's 128-VGPR cap):
//  * KC 32->16: staging regs 40 -> 20 (a4p[1] + b4p[4]).
//  * online argmin/softmax state (dm/km/Ss/Ts = 32 regs) removed from the
//    loop: per-chunk wave-reduced stats go to LDS cstat[4][64]; the 4-chunk
//    merge runs once at the end (same formula, ascending nc -> identical
//    first-occurrence tie semantics as the online version).
//  -> hot live set ~110 <= 128: no spill; LDS ~30 KB -> 4 blocks/CU at
//     VGPR<=128 (16 waves/CU of TLP).
// The per-(row,code) single-accumulator ascending-k fmaf chain is unchanged
// -> distances remain bit-exact vs the CPU BLAS reference.
__global__ __launch_bounds__(256,2) void fused_argmin_kernel(
    const float* __restrict__ X, const float* __restrict__ CB,
    const float* __restrict__ xsq, const float* __restrict__ csq,
    float* __restrict__ hist, float* __restrict__ acc_sc,
    float* __restrict__ out)
{
  __shared__ __align__(16) float As[KC][SA];        // 4.25 KB
  __shared__ __align__(16) float Bs[KC][SB];        // 16.25 KB
  __shared__ __align__(16) float cs_lds[K_CODES];   // 4 KB
  __shared__ __align__(16) float xs_lds[MT];
  __shared__ __align__(16) float4 cstat[4][MT];     // 4 KB: {dl, kl-bits, s1, t2s}
  __shared__ int sk[MT];
  const int t  = threadIdx.x;
  const int tx = t & 31, ty = t >> 5;   // 32 tx (codes) x 8 ty (8 rows each)
  const int m0 = blockIdx.x * MT;

  // ---- prologue: copy precomputed norms into LDS (coalesced) --------------
  reinterpret_cast<float4*>(cs_lds)[t] = reinterpret_cast<const float4*>(csq)[t];
  if(t < 16)
    reinterpret_cast<float4*>(xs_lds)[t] = reinterpret_cast<const float4*>(xsq + m0)[t];

  const int arow = t >> 2;            // 0..63 : row within tile
  const int acol = (t & 3) * 4;       // 0,4,8,12 : k offset (4 floats/thread)
  const float* Ag = X + (size_t)(m0 + arow)*DIMS + acol;

  // stage-0 register prefetch (nc=0, kc=0); overlaps the prologue barrier
  float4 a4p, b4p[4];
  a4p = *(const float4*)(Ag);
  {
    const float* Bg = CB + (size_t)t*DIMS;   // code t of chunk 0, k 0..15
    #pragma unroll
    for(int q=0;q<4;q++) b4p[q] = *(const float4*)(Bg + q*4);
  }
  __syncthreads();                    // cs_lds/xs_lds ready

  float xs_[8];
  { float4 x0 = *(const float4*)&xs_lds[ty*8];
    float4 x1 = *(const float4*)&xs_lds[ty*8+4];
    xs_[0]=x0.x; xs_[1]=x0.y; xs_[2]=x0.z; xs_[3]=x0.w;
    xs_[4]=x1.x; xs_[5]=x1.y; xs_[6]=x1.z; xs_[7]=x1.w; }

  for(int nc=0; nc<4; nc++){
    const int n0c = nc*NCHUNK;
    float acc[8][8];
    #pragma unroll
    for(int i=0;i<8;i++)
      #pragma unroll
      for(int j=0;j<8;j++) acc[i][j]=0.f;

    // K-chain: strictly ascending k=0..255, one fmaf chain per (row,code)
    for(int kc=0;kc<16;kc++){        // 16 stages of KC=16
      __syncthreads();
      // commit prefetched stage to LDS (k-major scatter; <=2-way = free)
      As[acol+0][arow]=a4p.x; As[acol+1][arow]=a4p.y;
      As[acol+2][arow]=a4p.z; As[acol+3][arow]=a4p.w;
      #pragma unroll
      for(int q=0;q<4;q++){
        Bs[q*4+0][t]=b4p[q].x; Bs[q*4+1][t]=b4p[q].y;
        Bs[q*4+2][t]=b4p[q].z; Bs[q*4+3][t]=b4p[q].w;
      }
      __syncthreads();
      // prefetch next stage; latency hides under the 1024-FMA compute phase
      {
        int nkc = kc+1, nnc = nc;
        if(nkc==16){ nkc=0; nnc=(nc+1)&3; }
        const float* An = Ag + nkc*KC;
        const float* Bn = CB + (size_t)(nnc*NCHUNK + t)*DIMS + nkc*KC;
        a4p = *(const float4*)(An);
        #pragma unroll
        for(int q=0;q<4;q++) b4p[q]=*(const float4*)(Bn + q*4);
      }
      #pragma unroll
      for(int k=0;k<KC;k++){
        float4 a0 = *(const float4*)&As[k][ty*8];
        float4 a1 = *(const float4*)&As[k][ty*8+4];
        float4 b0 = *(const float4*)&Bs[k][tx*4];
        float4 b1 = *(const float4*)&Bs[k][128 + tx*4];
        float a_[8]={a0.x,a0.y,a0.z,a0.w, a1.x,a1.y,a1.z,a1.w};
        float b_[8]={b0.x,b0.y,b0.z,b0.w, b1.x,b1.y,b1.z,b1.w};
        #pragma unroll
        for(int r=0;r<8;r++)
          #pragma unroll
          for(int j=0;j<8;j++)
            acc[r][j] = fmaf(a_[r], b_[j], acc[r][j]);
      }
    }

    // ---- chunk epilogue: d = sqrt(max(fl(fl(xs+cs) - 2*dot), 0)) -----------
    float csv[8];
    { float4 c0 = *(const float4*)&cs_lds[n0c + tx*4];
      float4 c1 = *(const float4*)&cs_lds[n0c + 128 + tx*4];
      csv[0]=c0.x; csv[1]=c0.y; csv[2]=c0.z; csv[3]=c0.w;
      csv[4]=c1.x; csv[5]=c1.y; csv[6]=c1.z; csv[7]=c1.w; }
    #pragma unroll
    for(int i=0;i<8;i++){
      float xs = xs_[i];
      float d[8];
      #pragma unroll
      for(int j=0;j<8;j++){
        // contraction-safe: 2*acc exact, fl(t - 2*acc)
        float d2 = (xs + csv[j]) - 2.0f*acc[i][j];
        d[j] = sqrtf(fmaxf(d2, 0.f));
      }
      // thread-local argmin, ascending kidx, strict < (first-occurrence tie)
      float dl = INFINITY; int kl = 0;
      #pragma unroll
      for(int j=0;j<8;j++){
        int kidx = n0c + (j>>2)*128 + tx*4 + (j&3);   // ascending in j
        if(d[j] < dl){ dl = d[j]; kl = kidx; }
      }
      // butterfly across the 32 tx lanes of this row group
      #pragma unroll
      for(int off=1; off<32; off<<=1){
        float od = __shfl_xor(dl, off, 64);
        int   ok = __shfl_xor(kl, off, 64);
        if(od < dl || (od == dl && ok < kl)){ dl = od; kl = ok; }
      }
      // chunk softmax stats shifted at chunk min: l = (dl - d)*100 <= 0
      float s1=0.f, t2s=0.f;
      #pragma unroll
      for(int j=0;j<8;j++){
        float l = (dl - d[j])*100.0f;
        float e = expf(l);
        s1 += e; t2s = fmaf(e, l, t2s);
      }
      #pragma unroll
      for(int off=1; off<32; off<<=1){
        s1  += __shfl_xor(s1,  off, 64);
        t2s += __shfl_xor(t2s, off, 64);
      }
      if(tx == 0)
        cstat[nc][ty*8 + i] = make_float4(dl, __int_as_float(kl), s1, t2s);
    }
  }

  // ---- final merge: one row per lane of wave 0 (ascending nc = same
  //      first-occurrence semantics as the online merge) -------------------
  __syncthreads();
  float plogp = 0.f;
  if(t < MT){
    float4 c0 = cstat[0][t];
    float dm = c0.x; int km = __float_as_int(c0.y);
    float Ss = c0.z; float Ts = c0.w;
    #pragma unroll
    for(int nc=1; nc<4; nc++){
      float4 cn = cstat[nc][t];
      float dl = cn.x; int kl = __float_as_int(cn.y);
      float s1 = cn.z, t2s = cn.w;
      if(dl < dm){                       // strict <: tie keeps old (smaller idx)
        float del = 100.0f*(dl - dm); float al = expf(del);
        Ts = al*(Ts + Ss*del) + t2s;
        Ss = al*Ss + s1;
        dm = dl; km = kl;
      } else {
        float del = 100.0f*(dm - dl); float al = expf(del);
        Ts += al*(t2s + s1*del);
        Ss += al*s1;
      }
    }
    int n = m0 + t;
    out[IDX_OFF + n] = (float)km;
    sk[t] = km;
    atomicAdd(hist + km, 1.0f);
    plogp = Ts/Ss - logf(Ss);
  }
  plogp = wsum64(plogp);
  if((t & 63) == 0) atomicAdd(acc_sc + 1, plogp);   // waves 1-3 add 0

  // ---- fused quant gather + mse -------------------------------------------
  __syncthreads();                 // sk[] visible to all waves
  {
    int w = t>>6, lane = t&63;     // 4 waves x 16 rows
    int row0 = w*16;
    float mse = 0.f;
    for(int r=0;r<16;r++){
      int n = m0 + row0 + r;
      int k = sk[row0 + r];
      float4 cb4 = *(const float4*)(CB + (size_t)k*DIMS + lane*4);
      float4 x4  = *(const float4*)(X  + (size_t)n*DIMS + lane*4);
      float e0=x4.x-cb4.x, e1=x4.y-cb4.y, e2=x4.z-cb4.z, e3=x4.w-cb4.w;
      mse += e0*e0 + e1*e1 + e2*e2 + e3*e3;
      *reinterpret_cast<float4*>(out + (size_t)n*DIMS + lane*4) = cb4;
    }
    mse = wsum64(mse);
    if(lane==0) atomicAdd(acc_sc+0, mse);
  }
}

// ---------------- finalize scalars (float32) --------------------------------
__global__ __launch_bounds__(256) void finalize_kernel(const float* __restrict__ hist,
                                                       const float* __restrict__ acc_sc,
                                                       float* __restrict__ out){
  __shared__ float red[256];
  int t = threadIdx.x;
  float s = 0.f;
  #pragma unroll
  for(int c=0;c<4;c++){
    float ap = hist[c*256 + t] * (1.0f/32768.0f);   // avg_probs ~ argmin histogram
    s += ap * logf(ap + 1e-5f);
  }
  red[t] = s; __syncthreads();
  for(int off=128; off; off>>=1){
    if(t<off) red[t]+=red[t+off];
    __syncthreads();
  }
  if(t==0){
    float avg_entropy    = -red[0];
    float mse            = acc_sc[0] * (1.0f/8388608.0f);
    float sample_entropy = -(acc_sc[1] * (1.0f/32768.0f));
    float commit = 0.5f*mse*0.25f;
    float cbl    = 0.5f*mse;
    float ent    = (sample_entropy - avg_entropy)*0.1f;
    float vq     = cbl + commit + ent;
    out[SC_OFF+0] = vq;
    out[SC_OFF+1] = commit;
    out[SC_OFF+2] = cbl;
    out[SC_OFF+3] = ent;
  }
}

extern "C" void kernel_launch(void* const* d_in, const int* in_sizes, int n_in,
                              void* d_out, int out_size, void* d_ws, size_t ws_size,
                              hipStream_t stream){
  const float* X  = (const float*)d_in[0];
  const float* CB = (const float*)d_in[1];
  float* out = (float*)d_out;                        // float32 output buffer
  float* xsq     = (float*)d_ws;                     // [32768]
  float* csq     = xsq + N_ROWS;                     // [1024]
  float* hist    = csq + K_CODES;                    // [1024]
  float* acc_sc  = hist + K_CODES;                   // [2]: mse, plogp

  hipMemsetAsync(hist, 0, (K_CODES+2)*sizeof(float), stream);
  rowsq_np512_kernel <<<(K_CODES+N_ROWS)/64, 256, 0, stream>>>(X, CB, xsq, csq);
  fused_argmin_kernel<<<N_ROWS/MT, 256, 0, stream>>>(X, CB, xsq, csq, hist, acc_sc, out);
  finalize_kernel    <<<1, 256, 0, stream>>>(hist, acc_sc, out);
}